// Round 15
// baseline (115.924 us; speedup 1.0000x reference)
//
#include <hip/hip_runtime.h>
#include <stdint.h>

typedef __attribute__((ext_vector_type(8))) short bf16x8;
typedef __attribute__((ext_vector_type(4))) float f32x4;

#define MFMA16(a, b, c) __builtin_amdgcn_mfma_f32_16x16x32_bf16((a), (b), (c), 0, 0, 0)

__device__ __forceinline__ void gload_lds16(const void* g, void* l) {
  __builtin_amdgcn_global_load_lds((const __attribute__((address_space(1))) void*)g,
                                   (__attribute__((address_space(3))) void*)l,
                                   16, 0, 0);
}

static __device__ __forceinline__ unsigned f2bf(float f) {
  union { float f; unsigned u; } cv;
  cv.f = f;
  return (cv.u + 0x7fffu + ((cv.u >> 16) & 1u)) >> 16;
}

#define BATCH 8192
#define ROWD  2128
#define KP1   2176           // padded row length (ushorts) in Ad
#define HID   512
#define LATD  256
#define KC1   272            // 8-elem k-chunks for layer 1 (272*8 = 2176)
#define NT1   68             // 32-k tiles
#define HSL_TW (BATCH * HID) // ushorts per tower in h_sl

// ---------- prep: k-chunked transpose-cast (both weight mats, one launch) ----------
__device__ __forceinline__ void tcast_body(
    const float* __restrict__ in, unsigned short* __restrict__ o,
    int s, int N, int lgN, int Kin, int perm)
{
  const int kc = s >> lgN, n = s & (N - 1);
  unsigned short v[8];
#pragma unroll
  for (int e = 0; e < 8; ++e) {
    const int k = kc * 8 + e;
    float f = 0.0f;
    if (k < Kin) {
      const int src = perm ? (k < 128 ? k + 2000 : k - 128) : k;
      f = in[(size_t)src * N + n];
    }
    v[e] = (unsigned short)f2bf(f);
  }
  *(uint4*)(o + (size_t)s * 8) = *(const uint4*)v;
}

__global__ __launch_bounds__(256) void ASAECF_tcast(
    const float* __restrict__ uW1, const float* __restrict__ iW1,
    const float* __restrict__ uW2, const float* __restrict__ iW2,
    unsigned short* __restrict__ w1s, unsigned short* __restrict__ w2s)
{
  const int tower = blockIdx.z;
  const int s = blockIdx.x * 256 + threadIdx.x;
  if (blockIdx.y == 0) {
    tcast_body(tower ? iW1 : uW1, w1s + (size_t)tower * KC1 * HID * 8,
               s, HID, 9, ROWD, 1);
  } else {
    if (blockIdx.x >= 64) return;
    tcast_body(tower ? iW2 : uW2, w2s + (size_t)tower * 64 * LATD * 8,
               s, LATD, 8, HID, 0);
  }
}

// ---------- agather: materialize gathered rows as dense bf16, burst reads ----------
// One wave per row: the 8.5-KB row is read CONTIGUOUSLY (DRAM row-buffer
// friendly), cast to bf16, written dense to Ad[tower][row][2176].
__global__ __launch_bounds__(256) void ASAECF_agather(
    const int* __restrict__ x,
    const float* __restrict__ ulook, const float* __restrict__ ilook,
    unsigned short* __restrict__ Ad)
{
  const int tower = blockIdx.y;
  const int row   = blockIdx.x * 4 + (threadIdx.x >> 6);
  const int lane  = threadIdx.x & 63;
  const float* __restrict__ look = tower ? ilook : ulook;
  const long long src = (long long)x[row * 2 + tower] * ROWD;
  unsigned short* dst = Ad + ((size_t)tower * BATCH + row) * KP1;

#pragma unroll
  for (int c = 0; c < 9; ++c) {
    const int k = c * 256 + lane * 4;
    if (c == 8 && lane >= 32) break;          // 2176 = 8*256 + 128
    f32x4 v = {0.0f, 0.0f, 0.0f, 0.0f};
    if (k + 4 <= ROWD)
      v = __builtin_nontemporal_load((const f32x4*)(look + src + k));
    uint2 p;
    p.x = f2bf(v[0]) | (f2bf(v[1]) << 16);
    p.y = f2bf(v[2]) | (f2bf(v[3]) << 16);
    *(uint2*)(dst + k) = p;
  }
}

// ---------- GEMM1: h = relu(Ad @ W1p + b1) ----------
// BM=128, BN=256 (nh half), BK=32, 512 thr = 8 waves, wave tile 128x32
// (R14 structure). A staged from DENSE bf16 Ad via ONE global_load_lds
// width-16 per thread per tile into double-buffered unpadded LDS [128][32].
// Grid = 64 mb x 2 nh x 2 towers = 256 blocks (1/CU), nh pair on same XCD.
__global__ __launch_bounds__(512) void ASAECF_gemm1(
    const unsigned short* __restrict__ Ad,    // [2][8192][2176]
    const unsigned short* __restrict__ w1s,   // [2][KC1][512][8]
    const float* __restrict__ ub1, const float* __restrict__ ib1,
    unsigned short* __restrict__ hsl)         // [2][chunk64][kc][row64][8]
{
  const int bid   = blockIdx.x;             // 0..255
  const int xcd   = bid & 7;
  const int idx   = bid >> 3;               // 0..31
  const int tower = xcd >> 2;
  const int nh    = idx & 1;
  const int mb    = (xcd & 3) * 16 + (idx >> 1);   // 0..63

  const unsigned short* __restrict__ Adt = Ad + (size_t)tower * BATCH * KP1;
  const unsigned short* __restrict__ w1 = w1s + (size_t)tower * KC1 * HID * 8;
  const float* __restrict__ b1 = tower ? ib1 : ub1;
  unsigned short* __restrict__ hout = hsl + (size_t)tower * HSL_TW;

  __shared__ unsigned short Ab[2][128 * 32];  // 8 KB per buffer, unpadded

  const int tid  = threadIdx.x;
  const int lane = tid & 63, wid = tid >> 6;  // wid 0..7 -> 32-col B slice
  const int fr   = lane & 15, fq = lane >> 4;
  const int row0 = mb * 128;

  // A staging: wave wid covers rows [wid*16, wid*16+16), lane -> (row, 16B chunk)
  const unsigned short* asrc =
      Adt + (size_t)(row0 + wid * 16 + (lane >> 2)) * KP1 + (lane & 3) * 8;
  auto stageA = [&](int t, int buf) {
    gload_lds16(asrc + t * 32, (char*)&Ab[buf][0] + wid * 1024 + lane * 16);
  };

  // B fragment offsets within one k-tile slab (4*512*8 ushorts)
  int boff[2];
#pragma unroll
  for (int n = 0; n < 2; ++n)
    boff[n] = (fq * 512 + nh * 256 + wid * 32 + n * 16 + fr) * 8;

  f32x4 acc[8][2] = {};
  bf16x8 bgc[2], bgn[2];

  // prologue: tile 0 staged; B(0) in flight
  stageA(0, 0);
#pragma unroll
  for (int n = 0; n < 2; ++n) bgc[n] = *(const bf16x8*)(w1 + boff[n]);
  __syncthreads();

#pragma unroll 2
  for (int t = 0; t < NT1; ++t) {
    const int cu = t & 1;
    if (t + 1 < NT1) stageA(t + 1, cu ^ 1);   // DMA into other buffer

    // B prefetch for t+1 (stays in flight through this tile's MFMAs)
    const unsigned short* bpn = w1 + (size_t)(t + 1) * (4 * 512 * 8);
#pragma unroll
    for (int n = 0; n < 2; ++n) bgn[n] = *(const bf16x8*)(bpn + boff[n]);

    bf16x8 af[8];
#pragma unroll
    for (int m = 0; m < 8; ++m)
      af[m] = *(const bf16x8*)&Ab[cu][(m * 16 + fr) * 32 + fq * 8];
#pragma unroll
    for (int n = 0; n < 2; ++n)
#pragma unroll
      for (int m = 0; m < 8; ++m)
        acc[m][n] = MFMA16(af[m], bgc[n], acc[m][n]);

#pragma unroll
    for (int n = 0; n < 2; ++n) bgc[n] = bgn[n];

    __syncthreads();   // staged tile ready; readers done with buf
  }

  // epilogue: bias + relu + store h in k-chunked slot layout
#pragma unroll
  for (int n = 0; n < 2; ++n) {
    const int col = nh * 256 + wid * 32 + n * 16 + fr;
    const int kc = col >> 3, e = col & 7;
    const float bb = b1[col];
#pragma unroll
    for (int m = 0; m < 8; ++m)
#pragma unroll
      for (int i = 0; i < 4; ++i) {
        const int rowib = m * 16 + fq * 4 + i;          // 0..127 within block
        const int chunk = mb * 2 + (rowib >> 6);
        const int row = rowib & 63;
        const float v = fmaxf(acc[m][n][i] + bb, 0.0f);
        hout[(((size_t)chunk * 64 + kc) * 64 + row) * 8 + e] = (unsigned short)f2bf(v);
      }
  }
}

// ---------- GEMM2 + dot, fully fused, no LDS staging ----------
__global__ __launch_bounds__(512, 2) void ASAECF_gemm2dot(
    const unsigned short* __restrict__ hsl,   // [2][chunk64][kc][row64][8]
    const unsigned short* __restrict__ w2s,   // [2][64][256][8]
    const float* __restrict__ ub2, const float* __restrict__ ib2,
    float* __restrict__ out)
{
  const int tid  = threadIdx.x;
  const int lane = tid & 63, wid = tid >> 6;
  const int fr   = lane & 15, fq = lane >> 4;
  const int rb   = blockIdx.x;          // 32-row block
  const int row0 = rb * 32;

  const unsigned short* __restrict__ hu = hsl;
  const unsigned short* __restrict__ hv = hsl + (size_t)HSL_TW;
  const size_t abase = ((size_t)(rb >> 1) * 64) * 64 * 8;
  const int lrow0 = (rb & 1) * 32;

  f32x4 au[2][2] = {}, av[2][2] = {};

#pragma unroll
  for (int t = 0; t < 8; ++t) {
#pragma unroll
    for (int s = 0; s < 2; ++s) {
      const int kc = t * 8 + s * 4 + fq;
      bf16x8 a_u[2], a_v[2], b_u[2], b_v[2];
#pragma unroll
      for (int m = 0; m < 2; ++m) {
        const size_t off = abase + ((size_t)kc * 64 + lrow0 + m * 16 + fr) * 8;
        a_u[m] = *(const bf16x8*)(hu + off);
        a_v[m] = *(const bf16x8*)(hv + off);
      }
#pragma unroll
      for (int n = 0; n < 2; ++n) {
        const int col = wid * 32 + n * 16 + fr;
        const size_t offb = ((size_t)kc * 256 + col) * 8;
        b_u[n] = *(const bf16x8*)(w2s + offb);
        b_v[n] = *(const bf16x8*)(w2s + (size_t)64 * 256 * 8 + offb);
      }
#pragma unroll
      for (int m = 0; m < 2; ++m)
#pragma unroll
        for (int n = 0; n < 2; ++n) {
          au[m][n] = MFMA16(a_u[m], b_u[n], au[m][n]);
          av[m][n] = MFMA16(a_v[m], b_v[n], av[m][n]);
        }
    }
  }

  // bias + per-row dot + reduction
  __shared__ float red[8][32];
  float bu[2], bv[2];
#pragma unroll
  for (int n = 0; n < 2; ++n) {
    const int col = wid * 32 + n * 16 + fr;
    bu[n] = ub2[col];
    bv[n] = ib2[col];
  }
#pragma unroll
  for (int m = 0; m < 2; ++m)
#pragma unroll
    for (int i = 0; i < 4; ++i) {
      float p = 0.0f;
#pragma unroll
      for (int n = 0; n < 2; ++n)
        p += (au[m][n][i] + bu[n]) * (av[m][n][i] + bv[n]);
      p += __shfl_xor(p, 1, 64);
      p += __shfl_xor(p, 2, 64);
      p += __shfl_xor(p, 4, 64);
      p += __shfl_xor(p, 8, 64);
      if (fr == 0) red[wid][m * 16 + fq * 4 + i] = p;
    }
  __syncthreads();
  if (tid < 32) {
    float s = 0.0f;
#pragma unroll
    for (int w = 0; w < 8; ++w) s += red[w][tid];
    out[row0 + tid] = s;
  }
}

extern "C" void kernel_launch(void* const* d_in, const int* in_sizes, int n_in,
                              void* d_out, int out_size, void* d_ws, size_t ws_size,
                              hipStream_t stream) {
  (void)in_sizes; (void)n_in; (void)out_size; (void)ws_size;
  const int*   x     = (const int*)d_in[0];
  const float* ulook = (const float*)d_in[1];
  const float* ilook = (const float*)d_in[2];
  const float* uW1   = (const float*)d_in[3];
  const float* ub1   = (const float*)d_in[4];
  const float* uW2   = (const float*)d_in[5];
  const float* ub2   = (const float*)d_in[6];
  const float* iW1   = (const float*)d_in[7];
  const float* ib1   = (const float*)d_in[8];
  const float* iW2   = (const float*)d_in[9];
  const float* ib2   = (const float*)d_in[10];
  float* out = (float*)d_out;

  // workspace layout (bytes):
  //   w1s: [2][272][512][8] bf16 =  4,456,448
  //   w2s: [2][64][256][8]  bf16 =    524,288  @  4,456,448
  //   hsl: [2][8192*512]    bf16 = 16,777,216  @  4,980,736
  //   Ad : [2][8192][2176]  bf16 = 71,303,168  @ 21,757,952
  char* ws = (char*)d_ws;
  unsigned short* w1s = (unsigned short*)(ws);
  unsigned short* w2s = (unsigned short*)(ws + 4456448);
  unsigned short* hsl = (unsigned short*)(ws + 4980736);
  unsigned short* Ad  = (unsigned short*)(ws + 21757952);

  ASAECF_tcast<<<dim3(544, 2, 2), 256, 0, stream>>>(uW1, iW1, uW2, iW2, w1s, w2s);
  ASAECF_agather<<<dim3(2048, 2), 256, 0, stream>>>(x, ulook, ilook, Ad);
  ASAECF_gemm1<<<dim3(256), 512, 0, stream>>>(Ad, w1s, ub1, ib1, hsl);
  ASAECF_gemm2dot<<<dim3(256), 512, 0, stream>>>(hsl, w2s, ub2, ib2, out);
}

// Round 16
// 110.634 us; speedup vs baseline: 1.0478x; 1.0478x over previous
//
#include <hip/hip_runtime.h>
#include <stdint.h>

typedef __attribute__((ext_vector_type(8))) short bf16x8;
typedef __attribute__((ext_vector_type(4))) float f32x4;

#define MFMA16(a, b, c) __builtin_amdgcn_mfma_f32_16x16x32_bf16((a), (b), (c), 0, 0, 0)

static __device__ __forceinline__ unsigned f2bf(float f) {
  union { float f; unsigned u; } cv;
  cv.f = f;
  return (cv.u + 0x7fffu + ((cv.u >> 16) & 1u)) >> 16;
}

#define BATCH 8192
#define ROWD  2128
#define HID   512
#define LATD  256
#define KC1   272            // 8-elem k-chunks for layer 1 (272*8 = 2176)
#define NTB   17             // 128-k tiles (17*128 = 2176)
#define SLAB  16384          // ushorts per 32-k B slab (4*512*8)
#define SUBT  5120           // ushorts per A sub-tile [128][40]
#define ABUF  20480          // ushorts per A buffer (4 sub-tiles)
#define HSL_TW (BATCH * HID) // ushorts per tower in h_sl

// ---------- prep: k-chunked transpose-cast (both weight mats, one launch) ----------
__device__ __forceinline__ void tcast_body(
    const float* __restrict__ in, unsigned short* __restrict__ o,
    int s, int N, int lgN, int Kin, int perm)
{
  const int kc = s >> lgN, n = s & (N - 1);
  unsigned short v[8];
#pragma unroll
  for (int e = 0; e < 8; ++e) {
    const int k = kc * 8 + e;
    float f = 0.0f;
    if (k < Kin) {
      const int src = perm ? (k < 128 ? k + 2000 : k - 128) : k;
      f = in[(size_t)src * N + n];
    }
    v[e] = (unsigned short)f2bf(f);
  }
  *(uint4*)(o + (size_t)s * 8) = *(const uint4*)v;
}

__global__ __launch_bounds__(256) void ASAECF_tcast(
    const float* __restrict__ uW1, const float* __restrict__ iW1,
    const float* __restrict__ uW2, const float* __restrict__ iW2,
    unsigned short* __restrict__ w1s, unsigned short* __restrict__ w2s)
{
  const int tower = blockIdx.z;
  const int s = blockIdx.x * 256 + threadIdx.x;
  if (blockIdx.y == 0) {
    tcast_body(tower ? iW1 : uW1, w1s + (size_t)tower * KC1 * HID * 8,
               s, HID, 9, ROWD, 1);
  } else {
    if (blockIdx.x >= 64) return;
    tcast_body(tower ? iW2 : uW2, w2s + (size_t)tower * 64 * LATD * 8,
               s, LATD, 8, HID, 0);
  }
}

// ---------- GEMM1: h = relu(gather(look) @ W1p + b1) ----------
// R14 skeleton (BM=128, BN=256 nh half, 8 waves, wave tile 128x32, grid 256,
// B read once per block from L2 slab) with BK=32 -> 128: 17 barriers instead
// of 68, each drain amortized under ~2480 cyc of MFMA. Per tile: issue next
// tile's B batch (8 loads) FIRST, then A-gather batch (8xf32x4) -> B uses get
// counted vmcnt (never drain A); writeA + barrier land after the MFMA wall.
__global__ __launch_bounds__(512) void ASAECF_gemm1(
    const int* __restrict__ x,
    const float* __restrict__ ulook, const float* __restrict__ ilook,
    const unsigned short* __restrict__ w1s,   // [2][KC1][512][8]
    const float* __restrict__ ub1, const float* __restrict__ ib1,
    unsigned short* __restrict__ hsl)         // [2][chunk64][kc][row64][8]
{
  extern __shared__ unsigned short Asl[];     // 2 x 4 x [128][40] = 81,920 B

  const int bid   = blockIdx.x;             // 0..255
  const int xcd   = bid & 7;
  const int idx   = bid >> 3;               // 0..31
  const int tower = xcd >> 2;
  const int nh    = idx & 1;                // nh pair adjacent on same XCD
  const int mb    = (xcd & 3) * 16 + (idx >> 1);   // 0..63

  const float* __restrict__ look = tower ? ilook : ulook;
  const unsigned short* __restrict__ w1 = w1s + (size_t)tower * KC1 * HID * 8;
  const float* __restrict__ b1 = tower ? ib1 : ub1;
  unsigned short* __restrict__ hout = hsl + (size_t)tower * HSL_TW;

  const int tid  = threadIdx.x;
  const int lane = tid & 63, wid = tid >> 6;  // wid 0..7 -> 32-col B slice
  const int fr   = lane & 15, fq = lane >> 4;
  const int row0 = mb * 128;

  // A staging: thread -> (row ar, sub-tile ks=tid&3, 32 consecutive k)
  const int ar = tid >> 2, ks0 = tid & 3;
  const long long arow = (long long)x[(row0 + ar) * 2 + tower] * ROWD + ks0 * 32;
  unsigned short* awr = &Asl[0] ;  // buf base added at use

  // B fragment offsets within one 32-k slab
  int boff[2];
#pragma unroll
  for (int n = 0; n < 2; ++n)
    boff[n] = (fq * 512 + nh * 256 + wid * 32 + n * 16 + fr) * 8;

  f32x4 rA[8];
  auto loadA = [&](int t) {
    const int kb = t * 128 + ks0 * 32;
#pragma unroll
    for (int j = 0; j < 8; ++j) {
      rA[j] = f32x4{0.0f, 0.0f, 0.0f, 0.0f};
      if (kb + j * 4 + 4 <= ROWD)
        rA[j] = *(const f32x4*)(look + arow + t * 128 + j * 4);
    }
  };
  auto writeA = [&](int buf) {
    unsigned short v[32];
#pragma unroll
    for (int j = 0; j < 8; ++j)
#pragma unroll
      for (int e = 0; e < 4; ++e)
        v[j * 4 + e] = (unsigned short)f2bf(rA[j][e]);
    unsigned short* d = &Asl[buf * ABUF + ks0 * SUBT + ar * 40];
#pragma unroll
    for (int c = 0; c < 4; ++c)
      *(bf16x8*)(d + c * 8) = *(const bf16x8*)(v + c * 8);
  };

  f32x4 acc[8][2] = {};
  bf16x8 Bc[4][2], Bn[4][2];

  // prologue: A(0) -> buf0; B slabs 0..3 -> Bc
  loadA(0);
  writeA(0);
#pragma unroll
  for (int s = 0; s < 4; ++s)
#pragma unroll
    for (int n = 0; n < 2; ++n)
      Bc[s][n] = *(const bf16x8*)(w1 + (size_t)s * SLAB + boff[n]);
  __syncthreads();

  for (int t = 0; t < NTB; ++t) {
    const int cu = t & 1;
    const bool pre = (t + 1 < NTB);
    if (pre) {
      // B batch for tile t+1 FIRST (so B uses never drain the A gather)
#pragma unroll
      for (int s = 0; s < 4; ++s)
#pragma unroll
        for (int n = 0; n < 2; ++n)
          Bn[s][n] = *(const bf16x8*)(w1 + (size_t)((t + 1) * 4 + s) * SLAB + boff[n]);
      loadA(t + 1);   // A gather batch (newest loads)
    }

    // 4 x 32-k sub-tiles: 64 MFMA/wave under one barrier
#pragma unroll
    for (int s = 0; s < 4; ++s) {
      bf16x8 af[8];
#pragma unroll
      for (int m = 0; m < 8; ++m)
        af[m] = *(const bf16x8*)&Asl[cu * ABUF + s * SUBT + (m * 16 + fr) * 40 + fq * 8];
#pragma unroll
      for (int n = 0; n < 2; ++n)
#pragma unroll
        for (int m = 0; m < 8; ++m)
          acc[m][n] = MFMA16(af[m], Bc[s][n], acc[m][n]);
    }

    if (pre) {
      writeA(cu ^ 1);
#pragma unroll
      for (int s = 0; s < 4; ++s)
#pragma unroll
        for (int n = 0; n < 2; ++n)
          Bc[s][n] = Bn[s][n];
    }
    __syncthreads();
  }

  // epilogue: bias + relu + store h in k-chunked slot layout
#pragma unroll
  for (int n = 0; n < 2; ++n) {
    const int col = nh * 256 + wid * 32 + n * 16 + fr;
    const int kc = col >> 3, e = col & 7;
    const float bb = b1[col];
#pragma unroll
    for (int m = 0; m < 8; ++m)
#pragma unroll
      for (int i = 0; i < 4; ++i) {
        const int rowib = m * 16 + fq * 4 + i;          // 0..127 within block
        const int chunk = mb * 2 + (rowib >> 6);
        const int row = rowib & 63;
        const float v = fmaxf(acc[m][n][i] + bb, 0.0f);
        hout[(((size_t)chunk * 64 + kc) * 64 + row) * 8 + e] = (unsigned short)f2bf(v);
      }
  }
}

// ---------- GEMM2 + dot, fully fused, no LDS staging ----------
__global__ __launch_bounds__(512, 2) void ASAECF_gemm2dot(
    const unsigned short* __restrict__ hsl,   // [2][chunk64][kc][row64][8]
    const unsigned short* __restrict__ w2s,   // [2][64][256][8]
    const float* __restrict__ ub2, const float* __restrict__ ib2,
    float* __restrict__ out)
{
  const int tid  = threadIdx.x;
  const int lane = tid & 63, wid = tid >> 6;
  const int fr   = lane & 15, fq = lane >> 4;
  const int rb   = blockIdx.x;          // 32-row block
  const int row0 = rb * 32;

  const unsigned short* __restrict__ hu = hsl;
  const unsigned short* __restrict__ hv = hsl + (size_t)HSL_TW;
  const size_t abase = ((size_t)(rb >> 1) * 64) * 64 * 8;
  const int lrow0 = (rb & 1) * 32;

  f32x4 au[2][2] = {}, av[2][2] = {};

#pragma unroll
  for (int t = 0; t < 8; ++t) {
#pragma unroll
    for (int s = 0; s < 2; ++s) {
      const int kc = t * 8 + s * 4 + fq;
      bf16x8 a_u[2], a_v[2], b_u[2], b_v[2];
#pragma unroll
      for (int m = 0; m < 2; ++m) {
        const size_t off = abase + ((size_t)kc * 64 + lrow0 + m * 16 + fr) * 8;
        a_u[m] = *(const bf16x8*)(hu + off);
        a_v[m] = *(const bf16x8*)(hv + off);
      }
#pragma unroll
      for (int n = 0; n < 2; ++n) {
        const int col = wid * 32 + n * 16 + fr;
        const size_t offb = ((size_t)kc * 256 + col) * 8;
        b_u[n] = *(const bf16x8*)(w2s + offb);
        b_v[n] = *(const bf16x8*)(w2s + (size_t)64 * 256 * 8 + offb);
      }
#pragma unroll
      for (int m = 0; m < 2; ++m)
#pragma unroll
        for (int n = 0; n < 2; ++n) {
          au[m][n] = MFMA16(a_u[m], b_u[n], au[m][n]);
          av[m][n] = MFMA16(a_v[m], b_v[n], av[m][n]);
        }
    }
  }

  // bias + per-row dot + reduction
  __shared__ float red[8][32];
  float bu[2], bv[2];
#pragma unroll
  for (int n = 0; n < 2; ++n) {
    const int col = wid * 32 + n * 16 + fr;
    bu[n] = ub2[col];
    bv[n] = ib2[col];
  }
#pragma unroll
  for (int m = 0; m < 2; ++m)
#pragma unroll
    for (int i = 0; i < 4; ++i) {
      float p = 0.0f;
#pragma unroll
      for (int n = 0; n < 2; ++n)
        p += (au[m][n][i] + bu[n]) * (av[m][n][i] + bv[n]);
      p += __shfl_xor(p, 1, 64);
      p += __shfl_xor(p, 2, 64);
      p += __shfl_xor(p, 4, 64);
      p += __shfl_xor(p, 8, 64);
      if (fr == 0) red[wid][m * 16 + fq * 4 + i] = p;
    }
  __syncthreads();
  if (tid < 32) {
    float s = 0.0f;
#pragma unroll
    for (int w = 0; w < 8; ++w) s += red[w][tid];
    out[row0 + tid] = s;
  }
}

extern "C" void kernel_launch(void* const* d_in, const int* in_sizes, int n_in,
                              void* d_out, int out_size, void* d_ws, size_t ws_size,
                              hipStream_t stream) {
  (void)in_sizes; (void)n_in; (void)out_size; (void)ws_size;
  const int*   x     = (const int*)d_in[0];
  const float* ulook = (const float*)d_in[1];
  const float* ilook = (const float*)d_in[2];
  const float* uW1   = (const float*)d_in[3];
  const float* ub1   = (const float*)d_in[4];
  const float* uW2   = (const float*)d_in[5];
  const float* ub2   = (const float*)d_in[6];
  const float* iW1   = (const float*)d_in[7];
  const float* ib1   = (const float*)d_in[8];
  const float* iW2   = (const float*)d_in[9];
  const float* ib2   = (const float*)d_in[10];
  float* out = (float*)d_out;

  // workspace layout (bytes):
  //   w1s: [2][272][512][8] bf16 = 4,456,448
  //   w2s: [2][64][256][8]  bf16 =   524,288  @ 4,456,448
  //   hsl: [2][8192*512]    bf16 = 16,777,216 @ 4,980,736
  char* ws = (char*)d_ws;
  unsigned short* w1s = (unsigned short*)(ws);
  unsigned short* w2s = (unsigned short*)(ws + 4456448);
  unsigned short* hsl = (unsigned short*)(ws + 4980736);

  ASAECF_tcast<<<dim3(544, 2, 2), 256, 0, stream>>>(uW1, iW1, uW2, iW2, w1s, w2s);
  ASAECF_gemm1<<<dim3(256), 512, 81920, stream>>>(x, ulook, ilook, w1s, ub1, ib1, hsl);
  ASAECF_gemm2dot<<<dim3(256), 512, 0, stream>>>(hsl, w2s, ub2, ib2, out);
}